// Round 1
// baseline (630.454 us; speedup 1.0000x reference)
//
#include <hip/hip_runtime.h>
#include <cmath>

#define PH 512
#define PW 512
#define KS 45
#define RAD 22
#define PLANE (PH * PW)
#define VROWS 32
#define VWIN (VROWS + 2 * RAD) /* 76 */

struct W45 { float w[KS]; };

// 8-consecutive-output 1D conv from a 52-float register window.
// WT.w[t_] with constant t_ stays in kernarg/SGPRs (1 sgpr read per VALU is free).
#define CONV8(win, WT, a)                                                     \
  do {                                                                        \
    _Pragma("unroll") for (int i_ = 0; i_ < 8; ++i_) a[i_] = 0.f;             \
    _Pragma("unroll") for (int t_ = 0; t_ < KS; ++t_) {                       \
      float wv_ = WT.w[t_];                                                   \
      _Pragma("unroll") for (int i_ = 0; i_ < 8; ++i_)                        \
        a[i_] = fmaf(wv_, win[i_ + t_], a[i_]);                               \
    }                                                                         \
  } while (0)

// ---------------- horizontal pass ----------------
// block = 256 = 4 rows x 64 lanes; each lane computes 8 consecutive x.
// grid.x = nplanes * 128
__global__ __launch_bounds__(256) void hpass_kernel(
    const float* __restrict__ s0, const float* __restrict__ s1,
    const float* __restrict__ sm, float* __restrict__ dst, int nimg, W45 wt) {
  const int tid = threadIdx.x;
  const int ry = tid >> 6;
  const int lr = tid & 63;
  const int p = blockIdx.x >> 7;
  const int rowg = blockIdx.x & 127;
  const int y = (rowg << 2) + ry;

  const int ni3 = nimg * 3;
  const float* src;
  if (p < ni3)          src = s0 + (size_t)p * PLANE;
  else if (p < 2 * ni3) src = s1 + (size_t)(p - ni3) * PLANE;
  else                  src = sm + (size_t)(p - 2 * ni3) * PLANE;
  const float* row = src + (size_t)y * PW;

  // Interleaved layout phys(i) = (i&7)*70 + (i>>3): window reads at fixed tap
  // are lane-consecutive -> bank-conflict-free (plain layout would be 16-way).
  __shared__ float lds[4][8 * 70];
  for (int i = lr; i < PW + 2 * RAD; i += 64) {
    int gx = i - RAD;
    gx = gx < 0 ? 0 : (gx > PW - 1 ? PW - 1 : gx);
    lds[ry][(i & 7) * 70 + (i >> 3)] = row[gx];
  }
  __syncthreads();

  const int x0 = lr << 3;
  float win[52];
#pragma unroll
  for (int j = 0; j < 52; ++j) {
    int i = x0 + j;
    win[j] = lds[ry][(i & 7) * 70 + (i >> 3)];
  }
  float a[8];
  CONV8(win, wt, a);

  float4* drow = (float4*)(dst + (size_t)p * PLANE + (size_t)y * PW + x0);
  drow[0] = make_float4(a[0], a[1], a[2], a[3]);
  drow[1] = make_float4(a[4], a[5], a[6], a[7]);
}

// ---------------- vertical helpers ----------------
__device__ __forceinline__ void v_loadwin(float (*lds)[64],
                                          const float* __restrict__ src,
                                          int x0, int y0, int lane, int yg) {
  for (int r = yg; r < VWIN; r += 4) {
    int gy = y0 + r - RAD;
    gy = gy < 0 ? 0 : (gy > PH - 1 ? PH - 1 : gy);
    lds[r][lane] = src[(size_t)gy * PW + x0 + lane];
  }
}

// ---------------- vertical pass, mask planes only ----------------
__global__ __launch_bounds__(256) void vmask_kernel(
    const float* __restrict__ tsrc, float* __restrict__ cur, int nimg, W45 wt) {
  const int tid = threadIdx.x;
  const int lane = tid & 63;
  const int yg = tid >> 6;
  const int p = blockIdx.x >> 7;
  const int t = blockIdx.x & 127;
  const int tx = t & 7, ty = t >> 3;
  const int x0 = tx << 6, y0 = ty << 5;
  const float* src = tsrc + (size_t)(6 * nimg + p) * PLANE;

  __shared__ float lds[VWIN][64];
  v_loadwin(lds, src, x0, y0, lane, yg);
  __syncthreads();

  float win[52];
#pragma unroll
  for (int j = 0; j < 52; ++j) win[j] = lds[(yg << 3) + j][lane];
  float a[8];
  CONV8(win, wt, a);

  float* d = cur + (size_t)(6 * nimg + p) * PLANE;
#pragma unroll
  for (int i = 0; i < 8; ++i)
    d[(size_t)(y0 + (yg << 3) + i) * PW + x0 + lane] = a[i];
}

// ---------------- vertical pass + blend for image planes ----------------
// LVL0: first level (acc = contrib, pre-blur inputs come from d_in)
// LVL3: last blurred level; also folds the final (non-blurred) level:
//       acc += c0 + m*((c1-c0)-d) + bm*d,  d = b1-b0   (b0 cancels)
template <bool LVL3, bool LVL0>
__global__ __launch_bounds__(256) void vcombine_kernel(
    const float* __restrict__ tsrc, float* __restrict__ cur,
    const float* __restrict__ pre0, const float* __restrict__ pre1,
    const float* __restrict__ prem, float* __restrict__ out, int nimg, W45 wt) {
  const int tid = threadIdx.x;
  const int lane = tid & 63;
  const int yg = tid >> 6;
  const int pc = blockIdx.x >> 7; /* (n,c) pair */
  const int t = blockIdx.x & 127;
  const int tx = t & 7, ty = t >> 3;
  const int x0 = tx << 6, y0 = ty << 5;
  const int n = pc / 3;

  __shared__ float lds[VWIN][64];
  float win[52];
  float b0[8], b1[8], bm[8];

  v_loadwin(lds, tsrc + (size_t)pc * PLANE, x0, y0, lane, yg);
  __syncthreads();
#pragma unroll
  for (int j = 0; j < 52; ++j) win[j] = lds[(yg << 3) + j][lane];
  CONV8(win, wt, b0);
  __syncthreads();

  v_loadwin(lds, tsrc + (size_t)(3 * nimg + pc) * PLANE, x0, y0, lane, yg);
  __syncthreads();
#pragma unroll
  for (int j = 0; j < 52; ++j) win[j] = lds[(yg << 3) + j][lane];
  CONV8(win, wt, b1);

  if (LVL3) {
    __syncthreads();
    v_loadwin(lds, tsrc + (size_t)(6 * nimg + n) * PLANE, x0, y0, lane, yg);
    __syncthreads();
#pragma unroll
    for (int j = 0; j < 52; ++j) win[j] = lds[(yg << 3) + j][lane];
    CONV8(win, wt, bm);
  }

  const size_t pix0 = (size_t)(y0 + (yg << 3)) * PW + x0 + lane;
  const size_t po0 = (size_t)pc * PLANE;
  const size_t po1 = (size_t)(3 * nimg + pc) * PLANE;
  const size_t pom = (size_t)n * PLANE;

#pragma unroll
  for (int i = 0; i < 8; ++i) {
    const size_t idx = pix0 + (size_t)i * PW;
    const float c0 = pre0[po0 + idx];
    const float c1 = pre1[po0 + idx];
    const float m = prem[pom + idx];
    if (!LVL3) {
      const float lap0 = c0 - b0[i];
      const float lap1 = c1 - b1[i];
      const float contrib = lap0 + m * (lap1 - lap0);
      const float prev = LVL0 ? 0.f : out[po0 + idx];
      out[po0 + idx] = prev + contrib;
      cur[po0 + idx] = b0[i];
      cur[po1 + idx] = b1[i];
    } else {
      const float d = b1[i] - b0[i];
      out[po0 + idx] = out[po0 + idx] + c0 + m * ((c1 - c0) - d) + bm[i] * d;
    }
  }
}

// ---------------- host ----------------
static void make_weights(W45& wt, int lvl) {
  double sigma = 1.0;
  for (int i = 0; i < lvl; ++i) sigma *= 2.0; // SIGMA0 * SIGMA_MULT^lvl
  double g[KS], sum = 0.0;
  for (int i = 0; i < KS; ++i) {
    double x = i - (KS - 1) / 2.0;
    g[i] = exp(-(x * x) / (2.0 * sigma * sigma));
    sum += g[i];
  }
  for (int i = 0; i < KS; ++i) wt.w[i] = (float)(g[i] / sum);
}

extern "C" void kernel_launch(void* const* d_in, const int* in_sizes, int n_in,
                              void* d_out, int out_size, void* d_ws,
                              size_t ws_size, hipStream_t stream) {
  const float* img0 = (const float*)d_in[0];
  const float* img1 = (const float*)d_in[1];
  const float* mask = (const float*)d_in[2];
  float* out = (float*)d_out;

  W45 wt[4];
  for (int l = 0; l < 4; ++l) make_weights(wt[l], l);

  const int NTOT = 16;
  // ws = cur(7*CN planes) + tmp(7*CN planes); pick largest CN that fits.
  const size_t perImg = (size_t)14 * PLANE * sizeof(float);
  int CN = 16;
  while (CN > 1 && (size_t)CN * perImg > ws_size) CN >>= 1;

  for (int s = 0; s < NTOT; s += CN) {
    float* cur = (float*)d_ws;
    float* tmp = cur + (size_t)7 * CN * PLANE;
    const float* in0 = img0 + (size_t)s * 3 * PLANE;
    const float* in1 = img1 + (size_t)s * 3 * PLANE;
    const float* inm = mask + (size_t)s * PLANE;
    float* o = out + (size_t)s * 3 * PLANE;

    float* c0r = cur;
    float* c1r = cur + (size_t)3 * CN * PLANE;
    float* cmr = cur + (size_t)6 * CN * PLANE;

    const dim3 blk(256);
    const int hblocks = 7 * CN * 128;
    const int vcblocks = 3 * CN * 128;
    const int vmblocks = CN * 128;

    // level 0: pre-blur values read straight from d_in
    hipLaunchKernelGGL(hpass_kernel, dim3(hblocks), blk, 0, stream, in0, in1,
                       inm, tmp, CN, wt[0]);
    hipLaunchKernelGGL((vcombine_kernel<false, true>), dim3(vcblocks), blk, 0,
                       stream, tmp, cur, in0, in1, inm, o, CN, wt[0]);
    hipLaunchKernelGGL(vmask_kernel, dim3(vmblocks), blk, 0, stream, tmp, cur,
                       CN, wt[0]);

    for (int l = 1; l <= 2; ++l) {
      hipLaunchKernelGGL(hpass_kernel, dim3(hblocks), blk, 0, stream, c0r, c1r,
                         cmr, tmp, CN, wt[l]);
      hipLaunchKernelGGL((vcombine_kernel<false, false>), dim3(vcblocks), blk,
                         0, stream, tmp, cur, c0r, c1r, cmr, o, CN, wt[l]);
      hipLaunchKernelGGL(vmask_kernel, dim3(vmblocks), blk, 0, stream, tmp, cur,
                         CN, wt[l]);
    }

    // level 3 (+ folded final level); bm computed in-kernel, no curm update
    hipLaunchKernelGGL(hpass_kernel, dim3(hblocks), blk, 0, stream, c0r, c1r,
                       cmr, tmp, CN, wt[3]);
    hipLaunchKernelGGL((vcombine_kernel<true, false>), dim3(vcblocks), blk, 0,
                       stream, tmp, cur, c0r, c1r, cmr, o, CN, wt[3]);
  }
}

// Round 3
// 603.231 us; speedup vs baseline: 1.0451x; 1.0451x over previous
//
#include <hip/hip_runtime.h>
#include <cmath>

#define PH 512
#define PW 512
#define KS 45
#define RAD 22
#define PLANE (PH * PW)
#define VWIN 108    /* 64 + 2*22 */
#define VSTRIDE 68  /* 68*4B = 272B: 16B-aligned rows, conflict-free column reads */
#define NF4 (VWIN * 16)

struct W45 { float w[KS]; };

// 8-consecutive-output 1D conv from a 52-float register window.
#define CONV8(win, WT, a)                                                     \
  do {                                                                        \
    _Pragma("unroll") for (int i_ = 0; i_ < 8; ++i_) a[i_] = 0.f;             \
    _Pragma("unroll") for (int t_ = 0; t_ < KS; ++t_) {                       \
      float wv_ = WT.w[t_];                                                   \
      _Pragma("unroll") for (int i_ = 0; i_ < 8; ++i_)                        \
        a[i_] = fmaf(wv_, win[i_ + t_], a[i_]);                               \
    }                                                                         \
  } while (0)

__device__ __forceinline__ int clampy(int y) {
  return y < 0 ? 0 : (y > PH - 1 ? PH - 1 : y);
}
__device__ __forceinline__ void ldf8(const float* __restrict__ p, float* v) {
  float4 a = *(const float4*)p, b = *(const float4*)(p + 4);
  v[0] = a.x; v[1] = a.y; v[2] = a.z; v[3] = a.w;
  v[4] = b.x; v[5] = b.y; v[6] = b.z; v[7] = b.w;
}
__device__ __forceinline__ void stf8(float* __restrict__ p, const float* v) {
  *(float4*)p = make_float4(v[0], v[1], v[2], v[3]);
  *(float4*)(p + 4) = make_float4(v[4], v[5], v[6], v[7]);
}

// ---------------- horizontal pass ------------------------------------------
__global__ __launch_bounds__(256) void hpass_kernel(
    const float* __restrict__ s0, const float* __restrict__ s1,
    const float* __restrict__ sm, float* __restrict__ dst, int nimg, W45 wt) {
  const int tid = threadIdx.x;
  const int ry = tid >> 6;
  const int lr = tid & 63;
  const int p = blockIdx.x >> 7;
  const int rowg = blockIdx.x & 127;
  const int y = (rowg << 2) + ry;

  const int ni3 = nimg * 3;
  const float* src;
  if (p < ni3)          src = s0 + (size_t)p * PLANE;
  else if (p < 2 * ni3) src = s1 + (size_t)(p - ni3) * PLANE;
  else                  src = sm + (size_t)(p - 2 * ni3) * PLANE;
  const float* row = src + (size_t)y * PW;

  __shared__ float lds[4][8 * 70];
  for (int i = lr; i < PW + 2 * RAD; i += 64) {
    int gx = i - RAD;
    gx = gx < 0 ? 0 : (gx > PW - 1 ? PW - 1 : gx);
    lds[ry][(i & 7) * 70 + (i >> 3)] = row[gx];
  }
  __syncthreads();

  const int x0 = lr << 3;
  float win[52];
#pragma unroll
  for (int j = 0; j < 52; ++j) {
    int i = x0 + j;
    win[j] = lds[ry][(i & 7) * 70 + (i >> 3)];
  }
  float a[8];
  CONV8(win, wt, a);

  float4* drow = (float4*)(dst + (size_t)p * PLANE + (size_t)y * PW + x0);
  drow[0] = make_float4(a[0], a[1], a[2], a[3]);
  drow[1] = make_float4(a[4], a[5], a[6], a[7]);
}

// ---------------- window loader: 64x64 tile, VWIN rows, float4 -------------
__device__ __forceinline__ void load_win2(float* buf0, float* buf1,
                                          const float* __restrict__ s0,
                                          const float* __restrict__ s1,
                                          int x0, int y0, int tid) {
  for (int r = 0; r < 4; ++r) {
    int idx = tid + (r << 9);
    if (idx < NF4) {
      int row = idx >> 4, c4 = (idx & 15) << 2;
      int gy = clampy(y0 + row - RAD);
      size_t g = (size_t)gy * PW + x0 + c4;
      *(float4*)&buf0[row * VSTRIDE + c4] = *(const float4*)&s0[g];
      *(float4*)&buf1[row * VSTRIDE + c4] = *(const float4*)&s1[g];
    }
  }
}
__device__ __forceinline__ void load_win1(float* buf0,
                                          const float* __restrict__ s0,
                                          int x0, int y0, int tid) {
  for (int r = 0; r < 4; ++r) {
    int idx = tid + (r << 9);
    if (idx < NF4) {
      int row = idx >> 4, c4 = (idx & 15) << 2;
      int gy = clampy(y0 + row - RAD);
      *(float4*)&buf0[row * VSTRIDE + c4] =
          *(const float4*)&s0[(size_t)gy * PW + x0 + c4];
    }
  }
}

// ---------------- fused V-pass + blend + mask blur (levels 0..2) -----------
// grid = (3*nimg + nimg) * 64 blocks of 512 threads; 64x64 output tile.
// pb < 3nimg: blend path (b0,b1 conv; lap-lerp accumulate; cur0/cur1 update)
// pb >= 3nimg: mask path (bm conv -> mdst)
// FIX vs R2: pre-blur values come from explicit pre0/pre1 (d_in at level 0;
// the cur region at levels 1-2). R2 read `cur` at level 0 = poisoned ws.
template <bool LVL0>
__global__ __launch_bounds__(512) void vblend_kernel(
    const float* __restrict__ tsrc, float* __restrict__ cur,
    float* __restrict__ mdst, const float* __restrict__ pre0,
    const float* __restrict__ pre1, const float* __restrict__ prem,
    float* __restrict__ out, int nimg, W45 wt) {
  __shared__ float buf0[VWIN * VSTRIDE];
  __shared__ float buf1[VWIN * VSTRIDE];
  const int tid = threadIdx.x;
  const int lane = tid & 63, yg = tid >> 6;
  const int pb = blockIdx.x >> 6, t = blockIdx.x & 63;
  const int x0 = (t & 7) << 6, y0 = (t >> 3) << 6;
  const int ni3 = 3 * nimg;
  const int ey = tid >> 3, exq = (tid & 7) << 3;  // epilogue: y-row, 8x chunk
  const size_t erow = (size_t)(y0 + ey) * PW + x0 + exq;

  if (pb >= ni3) {
    // ---- mask path ----
    const int pm = pb - ni3;
    load_win1(buf0, tsrc + (size_t)(6 * nimg + pm) * PLANE, x0, y0, tid);
    __syncthreads();
    float win[52];
#pragma unroll
    for (int j = 0; j < 52; ++j) win[j] = buf0[((yg << 3) + j) * VSTRIDE + lane];
    float a[8];
    CONV8(win, wt, a);
    __syncthreads();
#pragma unroll
    for (int i = 0; i < 8; ++i) buf0[lane * 65 + (yg << 3) + i] = a[i];
    __syncthreads();
    float bv[8];
#pragma unroll
    for (int j = 0; j < 8; ++j) bv[j] = buf0[(exq + j) * 65 + ey];
    stf8(mdst + (size_t)pm * PLANE + erow, bv);
    return;
  }

  // ---- blend path ----
  const int pc = pb;
  load_win2(buf0, buf1, tsrc + (size_t)pc * PLANE,
            tsrc + (size_t)(ni3 + pc) * PLANE, x0, y0, tid);
  __syncthreads();

  float win[52], b0[8], b1[8];
#pragma unroll
  for (int j = 0; j < 52; ++j) win[j] = buf0[((yg << 3) + j) * VSTRIDE + lane];
  CONV8(win, wt, b0);
#pragma unroll
  for (int j = 0; j < 52; ++j) win[j] = buf1[((yg << 3) + j) * VSTRIDE + lane];
  CONV8(win, wt, b1);

  __syncthreads();  // all window reads done -> safe to reuse bufs as stash
#pragma unroll
  for (int i = 0; i < 8; ++i) {
    buf0[lane * 65 + (yg << 3) + i] = b0[i];
    buf1[lane * 65 + (yg << 3) + i] = b1[i];
  }
  __syncthreads();

  // ---- vectorized epilogue: thread owns 8 consecutive x at one y ----
  float b0s[8], b1s[8];
#pragma unroll
  for (int j = 0; j < 8; ++j) {
    b0s[j] = buf0[(exq + j) * 65 + ey];
    b1s[j] = buf1[(exq + j) * 65 + ey];
  }
  float* c0p = cur + (size_t)pc * PLANE + erow;
  float* c1p = cur + (size_t)(ni3 + pc) * PLANE + erow;
  const float* p0p = pre0 + (size_t)pc * PLANE + erow;
  const float* p1p = pre1 + (size_t)pc * PLANE + erow;
  const float* mp = prem + (size_t)(pc / 3) * PLANE + erow;
  float* op = out + (size_t)pc * PLANE + erow;

  float c0v[8], c1v[8], m[8], pv[8], o[8];
  ldf8(p0p, c0v);  // read pre-blur values BEFORE overwriting cur (same thread)
  ldf8(p1p, c1v);
  ldf8(mp, m);
  if (!LVL0) ldf8(op, pv);
#pragma unroll
  for (int j = 0; j < 8; ++j) {
    float lap0 = c0v[j] - b0s[j];
    float lap1 = c1v[j] - b1s[j];
    float prev = LVL0 ? 0.f : pv[j];
    o[j] = prev + lap0 + m[j] * (lap1 - lap0);
  }
  stf8(op, o);
  stf8(c0p, b0s);
  stf8(c1p, b1s);
}

// ---------------- level-3 mask blur: bm -> separate buffer -----------------
__global__ __launch_bounds__(512) void vmask3_kernel(
    const float* __restrict__ src, float* __restrict__ dst, W45 wt) {
  __shared__ float buf0[VWIN * VSTRIDE];
  const int tid = threadIdx.x;
  const int lane = tid & 63, yg = tid >> 6;
  const int pm = blockIdx.x >> 6, t = blockIdx.x & 63;
  const int x0 = (t & 7) << 6, y0 = (t >> 3) << 6;
  const int ey = tid >> 3, exq = (tid & 7) << 3;

  load_win1(buf0, src + (size_t)pm * PLANE, x0, y0, tid);
  __syncthreads();
  float win[52];
#pragma unroll
  for (int j = 0; j < 52; ++j) win[j] = buf0[((yg << 3) + j) * VSTRIDE + lane];
  float a[8];
  CONV8(win, wt, a);
  __syncthreads();
#pragma unroll
  for (int i = 0; i < 8; ++i) buf0[lane * 65 + (yg << 3) + i] = a[i];
  __syncthreads();
  float bv[8];
#pragma unroll
  for (int j = 0; j < 8; ++j) bv[j] = buf0[(exq + j) * 65 + ey];
  stf8(dst + (size_t)pm * PLANE + (size_t)(y0 + ey) * PW + x0 + exq, bv);
}

// ---------------- level-3 combine (+ folded final level) -------------------
__global__ __launch_bounds__(512) void vcomb3_kernel(
    const float* __restrict__ tsrc, const float* __restrict__ cur,
    const float* __restrict__ prem, const float* __restrict__ bmb,
    float* __restrict__ out, int nimg, W45 wt) {
  __shared__ float buf0[VWIN * VSTRIDE];
  __shared__ float buf1[VWIN * VSTRIDE];
  const int tid = threadIdx.x;
  const int lane = tid & 63, yg = tid >> 6;
  const int pc = blockIdx.x >> 6, t = blockIdx.x & 63;
  const int x0 = (t & 7) << 6, y0 = (t >> 3) << 6;
  const int ni3 = 3 * nimg;
  const int ey = tid >> 3, exq = (tid & 7) << 3;
  const size_t erow = (size_t)(y0 + ey) * PW + x0 + exq;

  load_win2(buf0, buf1, tsrc + (size_t)pc * PLANE,
            tsrc + (size_t)(ni3 + pc) * PLANE, x0, y0, tid);
  __syncthreads();

  float win[52], b0[8], b1[8];
#pragma unroll
  for (int j = 0; j < 52; ++j) win[j] = buf0[((yg << 3) + j) * VSTRIDE + lane];
  CONV8(win, wt, b0);
#pragma unroll
  for (int j = 0; j < 52; ++j) win[j] = buf1[((yg << 3) + j) * VSTRIDE + lane];
  CONV8(win, wt, b1);

  __syncthreads();
#pragma unroll
  for (int i = 0; i < 8; ++i) {
    buf0[lane * 65 + (yg << 3) + i] = b0[i];
    buf1[lane * 65 + (yg << 3) + i] = b1[i];
  }
  __syncthreads();

  float b0s[8], b1s[8];
#pragma unroll
  for (int j = 0; j < 8; ++j) {
    b0s[j] = buf0[(exq + j) * 65 + ey];
    b1s[j] = buf1[(exq + j) * 65 + ey];
  }
  const int n = pc / 3;
  float c0v[8], c1v[8], m[8], bm[8], pv[8], o[8];
  ldf8(cur + (size_t)pc * PLANE + erow, c0v);
  ldf8(cur + (size_t)(ni3 + pc) * PLANE + erow, c1v);
  ldf8(prem + (size_t)n * PLANE + erow, m);
  ldf8(bmb + (size_t)n * PLANE + erow, bm);
  float* op = out + (size_t)pc * PLANE + erow;
  ldf8(op, pv);
#pragma unroll
  for (int j = 0; j < 8; ++j) {
    float d = b1s[j] - b0s[j];
    o[j] = pv[j] + c0v[j] + m[j] * ((c1v[j] - c0v[j]) - d) + bm[j] * d;
  }
  stf8(op, o);
}

// ---------------- host -----------------------------------------------------
static void make_weights(W45& wt, int lvl) {
  double sigma = 1.0;
  for (int i = 0; i < lvl; ++i) sigma *= 2.0;
  double g[KS], sum = 0.0;
  for (int i = 0; i < KS; ++i) {
    double x = i - (KS - 1) / 2.0;
    g[i] = exp(-(x * x) / (2.0 * sigma * sigma));
    sum += g[i];
  }
  for (int i = 0; i < KS; ++i) wt.w[i] = (float)(g[i] / sum);
}

extern "C" void kernel_launch(void* const* d_in, const int* in_sizes, int n_in,
                              void* d_out, int out_size, void* d_ws,
                              size_t ws_size, hipStream_t stream) {
  const float* img0 = (const float*)d_in[0];
  const float* img1 = (const float*)d_in[1];
  const float* mask = (const float*)d_in[2];
  float* out = (float*)d_out;

  W45 wt[4];
  for (int l = 0; l < 4; ++l) make_weights(wt[l], l);

  const int NTOT = 16;
  // ws planes per image: cur0(3) + cur1(3) + mA(1) + mB(1) + tmp(7) + bm(1) = 16
  const size_t perImg = (size_t)16 * PLANE * sizeof(float);
  int CN = 16;
  while (CN > 1 && (size_t)CN * perImg > ws_size) CN >>= 1;

  for (int s = 0; s < NTOT; s += CN) {
    float* base = (float*)d_ws;
    float* c0r = base;
    float* c1r = c0r + (size_t)3 * CN * PLANE;
    float* mA = c1r + (size_t)3 * CN * PLANE;
    float* mB = mA + (size_t)CN * PLANE;
    float* tmp = mB + (size_t)CN * PLANE;
    float* bm = tmp + (size_t)7 * CN * PLANE;

    const float* in0 = img0 + (size_t)s * 3 * PLANE;
    const float* in1 = img1 + (size_t)s * 3 * PLANE;
    const float* inm = mask + (size_t)s * PLANE;
    float* o = out + (size_t)s * 3 * PLANE;

    const dim3 b256(256), b512(512);
    const int hg = 7 * CN * 128;
    const int vg = 4 * CN * 64;
    const int v3g = 3 * CN * 64;
    const int mg = CN * 64;

    // level 0: pre-blur values read straight from d_in
    hipLaunchKernelGGL(hpass_kernel, dim3(hg), b256, 0, stream, in0, in1, inm,
                       tmp, CN, wt[0]);
    hipLaunchKernelGGL((vblend_kernel<true>), dim3(vg), b512, 0, stream, tmp,
                       c0r, mA, in0, in1, inm, o, CN, wt[0]);
    // level 1
    hipLaunchKernelGGL(hpass_kernel, dim3(hg), b256, 0, stream, c0r, c1r, mA,
                       tmp, CN, wt[1]);
    hipLaunchKernelGGL((vblend_kernel<false>), dim3(vg), b512, 0, stream, tmp,
                       c0r, mB, c0r, c1r, mA, o, CN, wt[1]);
    // level 2
    hipLaunchKernelGGL(hpass_kernel, dim3(hg), b256, 0, stream, c0r, c1r, mB,
                       tmp, CN, wt[2]);
    hipLaunchKernelGGL((vblend_kernel<false>), dim3(vg), b512, 0, stream, tmp,
                       c0r, mA, c0r, c1r, mB, o, CN, wt[2]);
    // level 3 (+ folded final level)
    hipLaunchKernelGGL(hpass_kernel, dim3(hg), b256, 0, stream, c0r, c1r, mA,
                       tmp, CN, wt[3]);
    hipLaunchKernelGGL(vmask3_kernel, dim3(mg), b512, 0, stream,
                       tmp + (size_t)6 * CN * PLANE, bm, wt[3]);
    hipLaunchKernelGGL(vcomb3_kernel, dim3(v3g), b512, 0, stream, tmp, c0r, mA,
                       bm, o, CN, wt[3]);
  }
}